// Round 2
// baseline (748.824 us; speedup 1.0000x reference)
//
#include <hip/hip_runtime.h>

#define NX   192
#define NXY  (192 * 192)          // 36864
#define N3   (192 * 192 * 192)    // 7077888
#define ZCHUNK 24

// 8th-order Laplacian coefficients (dx = 20, dx2 = 400), rounded from double
// exactly like JAX's python-scalar -> f32 weak promotion.
constexpr double DX2 = 400.0;
#define C0 ((float)(-205.0 / 72.0 / DX2 * 3.0))
#define C1 ((float)(8.0 / 5.0 / DX2))
#define C2 ((float)(-1.0 / 5.0 / DX2))
#define C3 ((float)(8.0 / 315.0 / DX2))
#define C4 ((float)(-1.0 / 560.0 / DX2))

// MODE: 0 = first step (prev == 0), 1 = middle step, 2 = last step (fused loss)
template <int MODE>
__global__ __launch_bounds__(256)
void step_kernel(const float* __restrict__ cur,
                 const float* __restrict__ prev,
                 const float* __restrict__ vp,
                 const float* __restrict__ src,
                 float* __restrict__ out,
                 const float* __restrict__ ref,
                 double* __restrict__ loss_sum,
                 unsigned int* __restrict__ max_bits)
{
    const int tx = threadIdx.x;            // 0..63
    const int ty = threadIdx.y;            // 0..3
    const int x  = blockIdx.x * 64 + tx;   // 0..191
    const int y  = blockIdx.y * 4 + ty;    // 0..191
    const int z0 = blockIdx.z * ZCHUNK;    // 0,24,...,168

    // tap validity (zero outside the domain, matching _shift_zero)
    const bool vxm1 = x >= 1, vxm2 = x >= 2, vxm3 = x >= 3, vxm4 = x >= 4;
    const bool vxp1 = x < NX - 1, vxp2 = x < NX - 2, vxp3 = x < NX - 3, vxp4 = x < NX - 4;
    const bool vym1 = y >= 1, vym2 = y >= 2, vym3 = y >= 3, vym4 = y >= 4;
    const bool vyp1 = y < NX - 1, vyp2 = y < NX - 2, vyp3 = y < NX - 3, vyp4 = y < NX - 4;

    const float* curcol = cur + (size_t)y * NX + x;   // column base (z index via *NXY)

    // sliding window over z: w0..w8 hold cur[z-4 .. z+4]
    auto ldz = [&](int z) -> float {
        return (z >= 0 && z < NX) ? curcol[(size_t)z * NXY] : 0.0f;
    };
    float w0 = ldz(z0 - 4);
    float w1 = ldz(z0 - 3);
    float w2 = ldz(z0 - 2);
    float w3 = ldz(z0 - 1);
    float w4 = ldz(z0 + 0);
    float w5 = ldz(z0 + 1);
    float w6 = ldz(z0 + 2);
    float w7 = ldz(z0 + 3);
    float w8;

    float facc = 0.0f;     // per-thread sum of err^2 (MODE==2)
    float fmax = 0.0f;     // per-thread max |err|   (MODE==2)

    size_t idx = (size_t)z0 * NXY + (size_t)y * NX + x;

    #pragma unroll 4
    for (int z = z0; z < z0 + ZCHUNK; ++z) {
        w8 = (z + 4 < NX) ? curcol[(size_t)(z + 4) * NXY] : 0.0f;

        const float* cp = cur + idx;
        const float center = w4;

        // d = 1..4 taps: ((((zm+zp)+ym)+yp)+xm)+xp  (mirrors reference order)
        float t1 = (w3 + w5);
        t1 += (vym1 ? cp[-1 * NX] : 0.0f);
        t1 += (vyp1 ? cp[ 1 * NX] : 0.0f);
        t1 += (vxm1 ? cp[-1] : 0.0f);
        t1 += (vxp1 ? cp[ 1] : 0.0f);

        float t2 = (w2 + w6);
        t2 += (vym2 ? cp[-2 * NX] : 0.0f);
        t2 += (vyp2 ? cp[ 2 * NX] : 0.0f);
        t2 += (vxm2 ? cp[-2] : 0.0f);
        t2 += (vxp2 ? cp[ 2] : 0.0f);

        float t3 = (w1 + w7);
        t3 += (vym3 ? cp[-3 * NX] : 0.0f);
        t3 += (vyp3 ? cp[ 3 * NX] : 0.0f);
        t3 += (vxm3 ? cp[-3] : 0.0f);
        t3 += (vxp3 ? cp[ 3] : 0.0f);

        float t4 = (w0 + w8);
        t4 += (vym4 ? cp[-4 * NX] : 0.0f);
        t4 += (vyp4 ? cp[ 4 * NX] : 0.0f);
        t4 += (vxm4 ? cp[-4] : 0.0f);
        t4 += (vxp4 ? cp[ 4] : 0.0f);

        float lap = C0 * center;
        lap += C1 * t1;
        lap += C2 * t2;
        lap += C3 * t3;
        lap += C4 * t4;

        float prevv;
        if constexpr (MODE == 0) prevv = 0.0f;
        else                     prevv = prev[idx];

        const float v = vp[idx];
        const float s = src[idx];
        const float upd = ((2.0f * center - prevv) + v * lap) + s;
        out[idx] = upd;

        if constexpr (MODE == 2) {
            const float err = upd - ref[idx];
            facc += err * err;
            fmax = fmaxf(fmax, fabsf(err));
        }

        // shift window
        w0 = w1; w1 = w2; w2 = w3; w3 = w4;
        w4 = w5; w5 = w6; w6 = w7; w7 = w8;
        idx += NXY;
    }

    if constexpr (MODE == 2) {
        // wave (64-lane) reduction
        double s = (double)facc;
        float  m = fmax;
        #pragma unroll
        for (int off = 32; off > 0; off >>= 1) {
            s += __shfl_down(s, off);
            m = fmaxf(m, __shfl_down(m, off));
        }
        __shared__ double sred[4];
        __shared__ float  mred[4];
        const int tid  = ty * 64 + tx;
        const int lane = tid & 63;
        const int wv   = tid >> 6;
        if (lane == 0) { sred[wv] = s; mred[wv] = m; }
        __syncthreads();
        if (tid == 0) {
            double st = (sred[0] + sred[1]) + (sred[2] + sred[3]);
            float  mt = fmaxf(fmaxf(mred[0], mred[1]), fmaxf(mred[2], mred[3]));
            atomicAdd(loss_sum, st);
            atomicMax(max_bits, __float_as_uint(mt));
        }
    }
}

__global__ void init_accum(double* loss_sum, unsigned int* max_bits)
{
    *loss_sum = 0.0;
    *max_bits = 0u;
}

__global__ void finalize_kernel(const double* loss_sum, const unsigned int* max_bits,
                                float* out)
{
    out[0]      = (float)(*loss_sum / (double)N3);
    out[N3 + 1] = __uint_as_float(*max_bits);
}

extern "C" void kernel_launch(void* const* d_in, const int* in_sizes, int n_in,
                              void* d_out, int out_size, void* d_ws, size_t ws_size,
                              hipStream_t stream)
{
    const float* vp     = (const float*)d_in[0];
    const float* srcall = (const float*)d_in[1];   // [10][N3]
    const float* ref    = (const float*)d_in[2];

    float* out = (float*)d_out;
    float* A   = out + 1;                 // field ping buffer (ends as final output)
    float* B   = (float*)d_ws;            // field pong buffer

    double*       lsum  = (double*)((char*)d_ws + (size_t)N3 * sizeof(float));
    unsigned int* mbits = (unsigned int*)(lsum + 1);

    const dim3 blk(64, 4, 1);
    const dim3 grd(NX / 64, NX / 4, NX / ZCHUNK);   // 3 x 48 x 8 = 1152 blocks

    init_accum<<<1, 1, 0, stream>>>(lsum, mbits);

    // t=0 folded: upd0 = s0 -> use source slice 0 directly as "cur" for t=1.
    // t=1: upd1 = 2*s0 + vp*lap(s0) + s1          -> A
    step_kernel<0><<<grd, blk, 0, stream>>>(srcall, nullptr, vp, srcall + (size_t)1 * N3,
                                            A, nullptr, nullptr, nullptr);
    // t=2: cur=A(upd1), prev=s0 (source slice 0)  -> B
    step_kernel<1><<<grd, blk, 0, stream>>>(A, srcall, vp, srcall + (size_t)2 * N3,
                                            B, nullptr, nullptr, nullptr);
    // t=3..8 ping-pong (write over prev's buffer; element-wise in-place is race-free)
    const float* cur = B;  const float* prv = A;  float* dst = A;
    for (int t = 3; t <= 8; ++t) {
        step_kernel<1><<<grd, blk, 0, stream>>>(cur, prv, vp, srcall + (size_t)t * N3,
                                                dst, nullptr, nullptr, nullptr);
        const float* ncur = dst;
        dst = (float*)cur;      // next writes over current prev... (ping-pong)
        prv = cur;
        cur = ncur;
    }
    // after loop: t=9 must have cur=upd8(B), prev=upd7(A), dst=A (== out+1)
    step_kernel<2><<<grd, blk, 0, stream>>>(cur, prv, vp, srcall + (size_t)9 * N3,
                                            (float*)dst, ref, lsum, mbits);

    finalize_kernel<<<1, 1, 0, stream>>>(lsum, mbits, out);
}

// Round 3
// 719.469 us; speedup vs baseline: 1.0408x; 1.0408x over previous
//
#include <hip/hip_runtime.h>

#define NX   192
#define NXY  (192 * 192)          // 36864
#define N3   (192 * 192 * 192)    // 7077888
#define ZCHUNK 8

typedef float f4 __attribute__((ext_vector_type(4)));

// 8th-order Laplacian coefficients (dx = 20, dx2 = 400)
constexpr double DX2 = 400.0;
#define C0 ((float)(-205.0 / 72.0 / DX2 * 3.0))
#define C1 ((float)(8.0 / 5.0 / DX2))
#define C2 ((float)(-1.0 / 5.0 / DX2))
#define C3 ((float)(8.0 / 315.0 / DX2))
#define C4 ((float)(-1.0 / 560.0 / DX2))

// x-tap lookup across the L|C|R register triple; j is compile-time constant
// after unroll, so the ternaries fold to a single register read.
#define AT(j) ((j) < 4 ? L[(j)] : ((j) < 8 ? C[(j) - 4] : R[(j) - 8]))

// MODE: 0 = first step (prev == 0), 1 = middle step, 2 = last step (fused loss)
template <int MODE>
__global__ __launch_bounds__(256)
void step_kernel(const float* __restrict__ cur,
                 const float* __restrict__ prev,
                 const float* __restrict__ vp,
                 const float* __restrict__ src,
                 float* __restrict__ out,
                 const float* __restrict__ ref,
                 double* __restrict__ loss_sum,
                 unsigned int* __restrict__ max_bits)
{
    const int tx = threadIdx.x;                 // 0..15
    const int ty = threadIdx.y;                 // 0..15
    const int x0 = blockIdx.x * 64 + tx * 4;    // 0,4,...,188
    const int y  = blockIdx.y * 16 + ty;        // 0..191
    const int z0 = blockIdx.z * ZCHUNK;

    const f4 zf4 = {0.0f, 0.0f, 0.0f, 0.0f};

    // x-halo validity: all-or-nothing per float4 (x0 is a multiple of 4, taps reach 4)
    const bool lvalid = (x0 != 0);
    const bool rvalid = (x0 != NX - 4);

    // y-tap validity (uniform per thread)
    const bool vym1 = y >= 1, vym2 = y >= 2, vym3 = y >= 3, vym4 = y >= 4;
    const bool vyp1 = y < NX - 1, vyp2 = y < NX - 2, vyp3 = y < NX - 3, vyp4 = y < NX - 4;

    const float* curcol = cur + (size_t)y * NX + x0;

    auto ldz = [&](int zz) -> f4 {
        return (zz >= 0 && zz < NX) ? *(const f4*)(curcol + (size_t)zz * NXY) : zf4;
    };

    // sliding z-window: w0..w8 = plane z-4 .. z+4 (this thread's own float4)
    f4 w0 = ldz(z0 - 4), w1 = ldz(z0 - 3), w2 = ldz(z0 - 2), w3 = ldz(z0 - 1);
    f4 w4 = ldz(z0), w5 = ldz(z0 + 1), w6 = ldz(z0 + 2), w7 = ldz(z0 + 3);
    f4 w8;

    float facc = 0.0f;   // sum err^2 (MODE==2)
    float fmax = 0.0f;   // max |err|  (MODE==2)

    size_t idx = (size_t)z0 * NXY + (size_t)y * NX + x0;

    for (int z = z0; z < z0 + ZCHUNK; ++z) {
        w8 = (z + 4 < NX) ? *(const f4*)(curcol + (size_t)(z + 4) * NXY) : zf4;

        const float* cp = cur + idx;

        // y taps (float4 covers all 4 points of this thread)
        const f4 ym1 = vym1 ? *(const f4*)(cp - 1 * NX) : zf4;
        const f4 yp1 = vyp1 ? *(const f4*)(cp + 1 * NX) : zf4;
        const f4 ym2 = vym2 ? *(const f4*)(cp - 2 * NX) : zf4;
        const f4 yp2 = vyp2 ? *(const f4*)(cp + 2 * NX) : zf4;
        const f4 ym3 = vym3 ? *(const f4*)(cp - 3 * NX) : zf4;
        const f4 yp3 = vyp3 ? *(const f4*)(cp + 3 * NX) : zf4;
        const f4 ym4 = vym4 ? *(const f4*)(cp - 4 * NX) : zf4;
        const f4 yp4 = vyp4 ? *(const f4*)(cp + 4 * NX) : zf4;

        // x halo
        const f4 L = lvalid ? *(const f4*)(cp - 4) : zf4;
        const f4 R = rvalid ? *(const f4*)(cp + 4) : zf4;
        const f4 C = w4;

        // partial tap sums in reference order: ((zm+zp)+ym)+yp   (then +xm, +xp per point)
        const f4 t1v = ((w3 + w5) + ym1) + yp1;
        const f4 t2v = ((w2 + w6) + ym2) + yp2;
        const f4 t3v = ((w1 + w7) + ym3) + yp3;
        const f4 t4v = ((w0 + w8) + ym4) + yp4;

        const f4 vpv = *(const f4*)(vp + idx);
        const f4 sv  = *(const f4*)(src + idx);
        f4 pv;
        if constexpr (MODE == 0) pv = zf4;
        else                     pv = *(const f4*)(prev + idx);

        f4 upd;
        #pragma unroll
        for (int i = 0; i < 4; ++i) {
            const float t1 = (t1v[i] + AT(4 + i - 1)) + AT(4 + i + 1);
            const float t2 = (t2v[i] + AT(4 + i - 2)) + AT(4 + i + 2);
            const float t3 = (t3v[i] + AT(4 + i - 3)) + AT(4 + i + 3);
            const float t4 = (t4v[i] + AT(4 + i - 4)) + AT(4 + i + 4);

            float lap = C0 * C[i];
            lap += C1 * t1;
            lap += C2 * t2;
            lap += C3 * t3;
            lap += C4 * t4;

            upd[i] = ((2.0f * C[i] - pv[i]) + vpv[i] * lap) + sv[i];
        }

        *(f4*)(out + idx) = upd;

        if constexpr (MODE == 2) {
            const f4 rv = *(const f4*)(ref + idx);
            #pragma unroll
            for (int i = 0; i < 4; ++i) {
                const float err = upd[i] - rv[i];
                facc += err * err;
                fmax = fmaxf(fmax, fabsf(err));
            }
        }

        // shift window
        w0 = w1; w1 = w2; w2 = w3; w3 = w4;
        w4 = w5; w5 = w6; w6 = w7; w7 = w8;
        idx += NXY;
    }

    if constexpr (MODE == 2) {
        double s = (double)facc;
        float  m = fmax;
        #pragma unroll
        for (int off = 32; off > 0; off >>= 1) {
            s += __shfl_down(s, off);
            m = fmaxf(m, __shfl_down(m, off));
        }
        __shared__ double sred[4];
        __shared__ float  mred[4];
        const int tid  = threadIdx.y * 16 + threadIdx.x;
        const int lane = tid & 63;
        const int wv   = tid >> 6;
        if (lane == 0) { sred[wv] = s; mred[wv] = m; }
        __syncthreads();
        if (tid == 0) {
            double st = (sred[0] + sred[1]) + (sred[2] + sred[3]);
            float  mt = fmaxf(fmaxf(mred[0], mred[1]), fmaxf(mred[2], mred[3]));
            atomicAdd(loss_sum, st);
            atomicMax(max_bits, __float_as_uint(mt));
        }
    }
}

__global__ void init_accum(double* loss_sum, unsigned int* max_bits)
{
    *loss_sum = 0.0;
    *max_bits = 0u;
}

__global__ void finalize_kernel(const double* loss_sum, const unsigned int* max_bits,
                                float* out)
{
    out[0]      = (float)(*loss_sum / (double)N3);
    out[N3 + 1] = __uint_as_float(*max_bits);
}

extern "C" void kernel_launch(void* const* d_in, const int* in_sizes, int n_in,
                              void* d_out, int out_size, void* d_ws, size_t ws_size,
                              hipStream_t stream)
{
    const float* vp     = (const float*)d_in[0];
    const float* srcall = (const float*)d_in[1];   // [10][N3]
    const float* ref    = (const float*)d_in[2];

    float* out = (float*)d_out;
    float* A   = out + 1;                 // field ping buffer (ends as final output)
    float* B   = (float*)d_ws;            // field pong buffer

    double*       lsum  = (double*)((char*)d_ws + (size_t)N3 * sizeof(float));
    unsigned int* mbits = (unsigned int*)(lsum + 1);

    const dim3 blk(16, 16, 1);
    const dim3 grd(NX / 64, NX / 16, NX / ZCHUNK);   // 3 x 12 x 24 = 864 blocks

    init_accum<<<1, 1, 0, stream>>>(lsum, mbits);

    // t=0 folded: upd0 = s0 -> use source slice 0 directly as "cur" for t=1.
    // t=1: upd1 = 2*s0 + vp*lap(s0) + s1          -> A
    step_kernel<0><<<grd, blk, 0, stream>>>(srcall, nullptr, vp, srcall + (size_t)1 * N3,
                                            A, nullptr, nullptr, nullptr);
    // t=2: cur=A(upd1), prev=s0 (source slice 0)  -> B
    step_kernel<1><<<grd, blk, 0, stream>>>(A, srcall, vp, srcall + (size_t)2 * N3,
                                            B, nullptr, nullptr, nullptr);
    // t=3..8 ping-pong (in-place over prev's buffer; element-wise, race-free)
    const float* cur = B;  const float* prv = A;  float* dst = A;
    for (int t = 3; t <= 8; ++t) {
        step_kernel<1><<<grd, blk, 0, stream>>>(cur, prv, vp, srcall + (size_t)t * N3,
                                                dst, nullptr, nullptr, nullptr);
        const float* ncur = dst;
        dst = (float*)cur;
        prv = cur;
        cur = ncur;
    }
    // t=9: cur=upd8(B), prev=upd7(A), dst=A (== out+1), fused loss
    step_kernel<2><<<grd, blk, 0, stream>>>(cur, prv, vp, srcall + (size_t)9 * N3,
                                            (float*)dst, ref, lsum, mbits);

    finalize_kernel<<<1, 1, 0, stream>>>(lsum, mbits, out);
}